// Round 1
// baseline (18031.807 us; speedup 1.0000x reference)
//
#include <hip/hip_runtime.h>
#include <hip/hip_bf16.h>

typedef unsigned short u16;
typedef __bf16 bf16x8 __attribute__((ext_vector_type(8)));
typedef float f32x4 __attribute__((ext_vector_type(4)));

#define B_ 64
#define T_ 256
#define I_ 256
#define H_ 512
#define O_ 256
#define D_ 16
#define NSLICE 32
#define NWG 128

__device__ __forceinline__ bf16x8 ld_bf8(const u16* p){
  uint4 u = *(const uint4*)p;
  return __builtin_bit_cast(bf16x8, u);
}

// ---------- elementwise prep: f32 -> bf16 hi/lo split ----------
__global__ __launch_bounds__(256) void k_split(const float* __restrict__ src,
    u16* __restrict__ hi, u16* __restrict__ lo, int n){
  int i = blockIdx.x*256 + threadIdx.x;
  if (i >= n) return;
  float v = src[i];
  __bf16 h = (__bf16)v;
  __bf16 l = (__bf16)(v - (float)h);
  hi[i] = __builtin_bit_cast(u16, h);
  lo[i] = __builtin_bit_cast(u16, l);
}

// ---------- cm[d][ho][i] = relu(0.125 - |d - clip(tau,1,16)|/64) * lateral ----------
__global__ __launch_bounds__(256) void k_prep_cm(const float* __restrict__ tau,
    const float* __restrict__ lat, u16* __restrict__ cmhi, u16* __restrict__ cmlo){
  int idx = blockIdx.x*256 + threadIdx.x;
  if (idx >= D_*H_*H_) return;
  int d = idx / (H_*H_) + 1;      // 1..16
  int r = idx % (H_*H_);
  float tc = fminf(fmaxf(tau[r], 1.0f), (float)D_);
  float cr = fmaxf(0.0f, 0.125f - fabsf((float)d - tc) * 0.015625f);
  float v = cr * lat[r];
  __bf16 h = (__bf16)v;
  __bf16 l = (__bf16)(v - (float)h);
  cmhi[idx] = __builtin_bit_cast(u16, h);
  cmlo[idx] = __builtin_bit_cast(u16, l);
}

// ---------- afferent: aff[t][b][ho] = x[b][t][:] . wa[ho][:] + ba[ho] (3-MFMA split) ----------
__global__ __launch_bounds__(256) void k_aff(const u16* __restrict__ xhi,
    const u16* __restrict__ xlo, const u16* __restrict__ wahi,
    const u16* __restrict__ walo, const float* __restrict__ ba,
    float* __restrict__ aff){
  int g = blockIdx.x;            // 1024 blocks
  int mg = g >> 2, ng = g & 3;   // 64-row m-group, 128-col n-group
  int tid = threadIdx.x;
  int w = tid >> 6, l = tid & 63;
  int lr = l & 15, lk8 = (l >> 4) * 8;
  f32x4 acc[4][2];
  #pragma unroll
  for (int a=0;a<4;++a){ acc[a][0]=(f32x4){0.f,0.f,0.f,0.f}; acc[a][1]=(f32x4){0.f,0.f,0.f,0.f}; }
  #pragma unroll 1
  for (int kk = 0; kk < 8; ++kk){
    int i = kk*32 + lk8;
    bf16x8 ahi[4], alo[4];
    #pragma unroll
    for (int mt = 0; mt < 4; ++mt){
      int r = mg*64 + mt*16 + lr;      // r = t*64 + b
      int t = r >> 6, b = r & 63;
      size_t off = ((size_t)b*T_ + t)*I_ + i;
      ahi[mt] = ld_bf8(xhi + off);
      alo[mt] = ld_bf8(xlo + off);
    }
    #pragma unroll
    for (int nj = 0; nj < 2; ++nj){
      int ho = ng*128 + w*32 + nj*16 + lr;
      bf16x8 bhi = ld_bf8(wahi + (size_t)ho*I_ + i);
      bf16x8 blo = ld_bf8(walo + (size_t)ho*I_ + i);
      #pragma unroll
      for (int mt = 0; mt < 4; ++mt){
        acc[mt][nj] = __builtin_amdgcn_mfma_f32_16x16x32_bf16(ahi[mt], bhi, acc[mt][nj],0,0,0);
        acc[mt][nj] = __builtin_amdgcn_mfma_f32_16x16x32_bf16(alo[mt], bhi, acc[mt][nj],0,0,0);
        acc[mt][nj] = __builtin_amdgcn_mfma_f32_16x16x32_bf16(ahi[mt], blo, acc[mt][nj],0,0,0);
      }
    }
  }
  #pragma unroll
  for (int mt=0; mt<4; ++mt)
    #pragma unroll
    for (int nj=0; nj<2; ++nj){
      int ho = ng*128 + w*32 + nj*16 + lr;
      float bias = ba[ho];
      #pragma unroll
      for (int r2=0;r2<4;++r2){
        int r = mg*64 + mt*16 + (l>>4)*4 + r2;
        aff[(size_t)r*H_ + ho] = acc[mt][nj][r2] + bias;   // aff[t][b][ho], r = t*64+b
      }
    }
}

// ---------- device-wide barrier: all-read-all flags, monotonic generations ----------
__device__ __forceinline__ void gbar(int* flags, int g, int tid, int gen){
  __threadfence();           // release own stores (agent scope)
  __syncthreads();           // all threads' fences done
  if (tid == 0)
    __hip_atomic_store(flags + g, gen, __ATOMIC_RELAXED, __HIP_MEMORY_SCOPE_AGENT);
  if (tid < 64){
    while (true){
      int f0 = __hip_atomic_load(flags + 2*tid,     __ATOMIC_RELAXED, __HIP_MEMORY_SCOPE_AGENT);
      int f1 = __hip_atomic_load(flags + 2*tid + 1, __ATOMIC_RELAXED, __HIP_MEMORY_SCOPE_AGENT);
      if (__all((f0 >= gen) && (f1 >= gen))) break;
      __builtin_amdgcn_s_sleep(1);
    }
  }
  __syncthreads();
  __threadfence();           // acquire before reading remote data
}

// ---------- persistent recurrence ----------
// WG g: n = g&3 (128-col n-group), k = g>>2 (K-slice: d = (k>>1)+1, i0 = (k&1)*256)
__global__ __launch_bounds__(256) void k_rec(const u16* __restrict__ cmhi,
    const u16* __restrict__ cmlo, const float* __restrict__ aff,
    u16* __restrict__ hhi, u16* __restrict__ hlo,
    float* __restrict__ partial, float* __restrict__ prelast,
    int* flags){
  __shared__ uint4 lds4[4096];         // 64 KiB: cm_hi slice [128 ho][256 k] bf16, XOR-swizzled
  char* lds = (char*)lds4;
  const int g = blockIdx.x;
  const int n = g & 3;
  const int k = g >> 2;
  const int d = (k >> 1) + 1;
  const int i0 = (k & 1) * 256;
  const int tid = threadIdx.x;
  const int w = tid >> 6, l = tid & 63;
  const int lr = l & 15, lk8 = (l >> 4) * 8;

  for (int it = tid; it < 4096; it += 256){
    int ho = it >> 5;
    int kc8 = (it & 31) * 8;
    uint4 v = *(const uint4*)(cmhi + (((size_t)(d-1)*H_ + n*128 + ho)*H_ + i0 + kc8));
    int byte = ho*512 + kc8*2;
    byte ^= (ho & 7) << 4;             // bank swizzle (G4)
    *(uint4*)(lds + byte) = v;
  }
  __syncthreads();

  const int c0 = g * 4;                // reduce ownership: 4 columns, all 64 batch rows
  const int rb = tid >> 2;
  const int rc = c0 + (tid & 3);

  for (int t = 0; t < T_; ++t){
    // ---- phase A: partial[k] = h[t-d][:, i0:i0+256] @ cm-slice^T ----
    if (d <= t){
      f32x4 acc[4][2];
      #pragma unroll
      for (int a=0;a<4;++a){ acc[a][0]=(f32x4){0.f,0.f,0.f,0.f}; acc[a][1]=(f32x4){0.f,0.f,0.f,0.f}; }
      const u16* hb = hhi + ((size_t)(t-d)*B_)*H_;
      const u16* lb = hlo + ((size_t)(t-d)*B_)*H_;
      #pragma unroll 1
      for (int kk = 0; kk < 8; ++kk){
        int i = i0 + kk*32 + lk8;
        bf16x8 ahi[4], alo[4];
        #pragma unroll
        for (int mt = 0; mt < 4; ++mt){
          int b = mt*16 + lr;
          ahi[mt] = ld_bf8(hb + (size_t)b*H_ + i);
          alo[mt] = ld_bf8(lb + (size_t)b*H_ + i);
        }
        #pragma unroll
        for (int nj = 0; nj < 2; ++nj){
          int holoc = w*32 + nj*16 + lr;
          int byte = holoc*512 + (kk*32 + lk8)*2;
          byte ^= (holoc & 7) << 4;
          bf16x8 bhi = __builtin_bit_cast(bf16x8, *(const uint4*)(lds + byte));
          bf16x8 blo = ld_bf8(cmlo + (((size_t)(d-1)*H_ + n*128 + holoc)*H_ + i));
          #pragma unroll
          for (int mt = 0; mt < 4; ++mt){
            acc[mt][nj] = __builtin_amdgcn_mfma_f32_16x16x32_bf16(ahi[mt], bhi, acc[mt][nj],0,0,0);
            acc[mt][nj] = __builtin_amdgcn_mfma_f32_16x16x32_bf16(alo[mt], bhi, acc[mt][nj],0,0,0);
            acc[mt][nj] = __builtin_amdgcn_mfma_f32_16x16x32_bf16(ahi[mt], blo, acc[mt][nj],0,0,0);
          }
        }
      }
      #pragma unroll
      for (int mt=0; mt<4; ++mt)
        #pragma unroll
        for (int nj=0; nj<2; ++nj){
          int ho = n*128 + w*32 + nj*16 + lr;
          #pragma unroll
          for (int r2=0;r2<4;++r2){
            int b = mt*16 + (l>>4)*4 + r2;
            partial[((size_t)k*B_ + b)*H_ + ho] = acc[mt][nj][r2];
          }
        }
    } // else: region stays zero from launch-time memset

    gbar(flags, g, tid, 2*t+1);

    // ---- phase R: reduce 32 partials, +aff, tanh, write h hi/lo (or pre_last at t=255) ----
    {
      float s = 0.f;
      #pragma unroll
      for (int kq = 0; kq < NSLICE; ++kq)
        s += partial[((size_t)kq*B_ + rb)*H_ + rc];
      if (t < T_-1){
        float hv = tanhf(aff[((size_t)t*B_ + rb)*H_ + rc] + s);
        __bf16 hh = (__bf16)hv;
        __bf16 hl = (__bf16)(hv - (float)hh);
        hhi[((size_t)t*B_ + rb)*H_ + rc] = __builtin_bit_cast(u16, hh);
        hlo[((size_t)t*B_ + rb)*H_ + rc] = __builtin_bit_cast(u16, hl);
      } else {
        prelast[(size_t)rb*H_ + rc] = s;   // h_delayed(255), pre-efferent
      }
    }

    gbar(flags, g, tid, 2*t+2);
  }
}

// ---------- y[b][o] = pre_last[b][:] . we[o][:] + be[o] (pure f32) ----------
__global__ __launch_bounds__(256) void k_out(const float* __restrict__ prelast,
    const float* __restrict__ we, const float* __restrict__ be, float* __restrict__ y){
  int idx = blockIdx.x*256 + threadIdx.x;
  int b = idx >> 8, o = idx & 255;
  const float4* pa = (const float4*)(prelast + (size_t)b*H_);
  const float4* wb = (const float4*)(we + (size_t)o*H_);
  float s = 0.f;
  #pragma unroll 8
  for (int i2 = 0; i2 < H_/4; ++i2){
    float4 p = pa[i2], q = wb[i2];
    s += p.x*q.x + p.y*q.y + p.z*q.z + p.w*q.w;
  }
  y[idx] = s + be[o];
}

extern "C" void kernel_launch(void* const* d_in, const int* in_sizes, int n_in,
                              void* d_out, int out_size, void* d_ws, size_t ws_size,
                              hipStream_t stream){
  (void)in_sizes; (void)n_in; (void)out_size; (void)ws_size;
  const float* x   = (const float*)d_in[0];
  const float* wa  = (const float*)d_in[1];
  const float* ba  = (const float*)d_in[2];
  const float* lat = (const float*)d_in[3];
  const float* tau = (const float*)d_in[4];
  const float* we  = (const float*)d_in[5];
  const float* be  = (const float*)d_in[6];
  float* y = (float*)d_out;

  char* ws = (char*)d_ws;
  size_t cur = 0;
  auto alloc = [&](size_t sz) -> void* {
    void* p = ws + cur;
    cur += (sz + 255) & ~(size_t)255;
    return p;
  };
  int*   flags   = (int*)  alloc(4096);
  float* partial = (float*)alloc((size_t)NSLICE*B_*H_*4);   // contiguous with flags for one memset
  u16* xhi = (u16*)alloc((size_t)B_*T_*I_*2);
  u16* xlo = (u16*)alloc((size_t)B_*T_*I_*2);
  u16* wahi= (u16*)alloc((size_t)H_*I_*2);
  u16* walo= (u16*)alloc((size_t)H_*I_*2);
  u16* cmhi= (u16*)alloc((size_t)D_*H_*H_*2);
  u16* cmlo= (u16*)alloc((size_t)D_*H_*H_*2);
  float* aff = (float*)alloc((size_t)T_*B_*H_*4);
  u16* hhi = (u16*)alloc((size_t)T_*B_*H_*2);
  u16* hlo = (u16*)alloc((size_t)T_*B_*H_*2);
  float* prelast = (float*)alloc((size_t)B_*H_*4);

  // zero barrier flags + partial accumulators (re-poisoned by harness each launch)
  hipMemsetAsync(flags, 0, 4096 + (size_t)NSLICE*B_*H_*4, stream);

  k_split<<<(B_*T_*I_+255)/256, 256, 0, stream>>>(x, xhi, xlo, B_*T_*I_);
  k_split<<<(H_*I_+255)/256,   256, 0, stream>>>(wa, wahi, walo, H_*I_);
  k_prep_cm<<<(D_*H_*H_+255)/256, 256, 0, stream>>>(tau, lat, cmhi, cmlo);
  k_aff<<<1024, 256, 0, stream>>>(xhi, xlo, wahi, walo, ba, aff);
  k_rec<<<NWG, 256, 0, stream>>>(cmhi, cmlo, aff, hhi, hlo, partial, prelast, flags);
  k_out<<<(B_*O_+255)/256, 256, 0, stream>>>(prelast, we, be, y);
}

// Round 2
// 9023.415 us; speedup vs baseline: 1.9983x; 1.9983x over previous
//
#include <hip/hip_runtime.h>
#include <hip/hip_bf16.h>

typedef unsigned short u16;
typedef unsigned int u32;
typedef __bf16 bf16x8 __attribute__((ext_vector_type(8)));
typedef float f32x4 __attribute__((ext_vector_type(4)));

#define B_ 64
#define T_ 256
#define I_ 256
#define H_ 512
#define O_ 256
#define D_ 16
#define NSLICE 32
#define NWG 128

__device__ __forceinline__ bf16x8 ld_bf8(const u16* p){
  uint4 u = *(const uint4*)p;
  return __builtin_bit_cast(bf16x8, u);
}

// coherent (cross-XCD) helpers: agent-scope relaxed atomics -> sc0 sc1 ops
__device__ __forceinline__ void st_coh_f32(float* p, float v){
  __hip_atomic_store(p, v, __ATOMIC_RELAXED, __HIP_MEMORY_SCOPE_AGENT);
}
__device__ __forceinline__ float ld_coh_f32(const float* p){
  return __hip_atomic_load(p, __ATOMIC_RELAXED, __HIP_MEMORY_SCOPE_AGENT);
}
__device__ __forceinline__ void st_coh_u32(u32* p, u32 v){
  __hip_atomic_store(p, v, __ATOMIC_RELAXED, __HIP_MEMORY_SCOPE_AGENT);
}

// ---------- elementwise prep: f32 -> bf16 hi/lo split ----------
__global__ __launch_bounds__(256) void k_split(const float* __restrict__ src,
    u16* __restrict__ hi, u16* __restrict__ lo, int n){
  int i = blockIdx.x*256 + threadIdx.x;
  if (i >= n) return;
  float v = src[i];
  __bf16 h = (__bf16)v;
  __bf16 l = (__bf16)(v - (float)h);
  hi[i] = __builtin_bit_cast(u16, h);
  lo[i] = __builtin_bit_cast(u16, l);
}

// ---------- cm[d][ho][i] = relu(0.125 - |d - clip(tau,1,16)|/64) * lateral ----------
__global__ __launch_bounds__(256) void k_prep_cm(const float* __restrict__ tau,
    const float* __restrict__ lat, u16* __restrict__ cmhi, u16* __restrict__ cmlo){
  int idx = blockIdx.x*256 + threadIdx.x;
  if (idx >= D_*H_*H_) return;
  int d = idx / (H_*H_) + 1;      // 1..16
  int r = idx % (H_*H_);
  float tc = fminf(fmaxf(tau[r], 1.0f), (float)D_);
  float cr = fmaxf(0.0f, 0.125f - fabsf((float)d - tc) * 0.015625f);
  float v = cr * lat[r];
  __bf16 h = (__bf16)v;
  __bf16 l = (__bf16)(v - (float)h);
  cmhi[idx] = __builtin_bit_cast(u16, h);
  cmlo[idx] = __builtin_bit_cast(u16, l);
}

// ---------- afferent: aff[t][b][ho] = x[b][t][:] . wa[ho][:] + ba[ho] (3-MFMA split) ----------
__global__ __launch_bounds__(256) void k_aff(const u16* __restrict__ xhi,
    const u16* __restrict__ xlo, const u16* __restrict__ wahi,
    const u16* __restrict__ walo, const float* __restrict__ ba,
    float* __restrict__ aff){
  int g = blockIdx.x;            // 1024 blocks
  int mg = g >> 2, ng = g & 3;   // 64-row m-group, 128-col n-group
  int tid = threadIdx.x;
  int w = tid >> 6, l = tid & 63;
  int lr = l & 15, lk8 = (l >> 4) * 8;
  f32x4 acc[4][2];
  #pragma unroll
  for (int a=0;a<4;++a){ acc[a][0]=(f32x4){0.f,0.f,0.f,0.f}; acc[a][1]=(f32x4){0.f,0.f,0.f,0.f}; }
  #pragma unroll 1
  for (int kk = 0; kk < 8; ++kk){
    int i = kk*32 + lk8;
    bf16x8 ahi[4], alo[4];
    #pragma unroll
    for (int mt = 0; mt < 4; ++mt){
      int r = mg*64 + mt*16 + lr;      // r = t*64 + b
      int t = r >> 6, b = r & 63;
      size_t off = ((size_t)b*T_ + t)*I_ + i;
      ahi[mt] = ld_bf8(xhi + off);
      alo[mt] = ld_bf8(xlo + off);
    }
    #pragma unroll
    for (int nj = 0; nj < 2; ++nj){
      int ho = ng*128 + w*32 + nj*16 + lr;
      bf16x8 bhi = ld_bf8(wahi + (size_t)ho*I_ + i);
      bf16x8 blo = ld_bf8(walo + (size_t)ho*I_ + i);
      #pragma unroll
      for (int mt = 0; mt < 4; ++mt){
        acc[mt][nj] = __builtin_amdgcn_mfma_f32_16x16x32_bf16(ahi[mt], bhi, acc[mt][nj],0,0,0);
        acc[mt][nj] = __builtin_amdgcn_mfma_f32_16x16x32_bf16(alo[mt], bhi, acc[mt][nj],0,0,0);
        acc[mt][nj] = __builtin_amdgcn_mfma_f32_16x16x32_bf16(ahi[mt], blo, acc[mt][nj],0,0,0);
      }
    }
  }
  #pragma unroll
  for (int mt=0; mt<4; ++mt)
    #pragma unroll
    for (int nj=0; nj<2; ++nj){
      int ho = ng*128 + w*32 + nj*16 + lr;
      float bias = ba[ho];
      #pragma unroll
      for (int r2=0;r2<4;++r2){
        int r = mg*64 + mt*16 + (l>>4)*4 + r2;
        aff[(size_t)r*H_ + ho] = acc[mt][nj][r2] + bias;   // aff[t][b][ho], r = t*64+b
      }
    }
}

// ---------- device-wide barrier: all-read-all flags, monotonic generations ----------
// NO __threadfence(): cross-WG data uses coherent (sc0 sc1) ops; the
// vmcnt(0) drain before s_barrier orders write-through stores before the flag.
__device__ __forceinline__ void gbar(int* flags, int g, int tid, int gen){
  asm volatile("s_waitcnt vmcnt(0)" ::: "memory");
  __syncthreads();
  if (tid == 0)
    __hip_atomic_store(flags + g, gen, __ATOMIC_RELAXED, __HIP_MEMORY_SCOPE_AGENT);
  if (tid < 64){
    while (true){
      int f0 = __hip_atomic_load(flags + 2*tid,     __ATOMIC_RELAXED, __HIP_MEMORY_SCOPE_AGENT);
      int f1 = __hip_atomic_load(flags + 2*tid + 1, __ATOMIC_RELAXED, __HIP_MEMORY_SCOPE_AGENT);
      if (__all((f0 >= gen) && (f1 >= gen))) break;
      __builtin_amdgcn_s_sleep(1);
    }
  }
  __syncthreads();
}

// ---------- persistent recurrence ----------
// WG g: n = g&3 (128-col n-group), k = g>>2 (K-slice: d = (k>>1)+1, i0 = (k&1)*256)
__global__ __launch_bounds__(256) void k_rec(const u16* __restrict__ cmhi,
    const u16* __restrict__ cmlo, const float* __restrict__ aff,
    u16* __restrict__ hhi, u16* __restrict__ hlo,
    float* __restrict__ partial, float* __restrict__ prelast,
    int* flags){
  __shared__ uint4 lds4[4096];         // 64 KiB: cm_hi slice [128 ho][256 k] bf16, XOR-swizzled
  __shared__ float4 red[3][64];        // reduce combine buffer
  char* lds = (char*)lds4;
  const int g = blockIdx.x;
  const int n = g & 3;
  const int k = g >> 2;
  const int d = (k >> 1) + 1;
  const int i0 = (k & 1) * 256;
  const int tid = threadIdx.x;
  const int w = tid >> 6, l = tid & 63;
  const int lr = l & 15, lk8 = (l >> 4) * 8;

  for (int it = tid; it < 4096; it += 256){
    int ho = it >> 5;
    int kc8 = (it & 31) * 8;
    uint4 v = *(const uint4*)(cmhi + (((size_t)(d-1)*H_ + n*128 + ho)*H_ + i0 + kc8));
    int byte = ho*512 + kc8*2;
    byte ^= (ho & 7) << 4;             // bank swizzle (G4)
    *(uint4*)(lds + byte) = v;
  }
  __syncthreads();

  const int c0 = g * 4;                // reduce ownership: 4 cols, all 64 batch rows

  for (int t = 0; t < T_; ++t){
    // ---- phase A: partial[k] = h[t-d][:, i0:i0+256] @ cm-slice^T ----
    if (d <= t){
      f32x4 acc[4][2];
      #pragma unroll
      for (int a=0;a<4;++a){ acc[a][0]=(f32x4){0.f,0.f,0.f,0.f}; acc[a][1]=(f32x4){0.f,0.f,0.f,0.f}; }
      const u16* hb = hhi + ((size_t)(t-d)*B_)*H_;
      const u16* lb = hlo + ((size_t)(t-d)*B_)*H_;
      #pragma unroll 1
      for (int kk = 0; kk < 8; ++kk){
        int i = i0 + kk*32 + lk8;
        bf16x8 ahi[4], alo[4];
        #pragma unroll
        for (int mt = 0; mt < 4; ++mt){
          int b = mt*16 + lr;
          ahi[mt] = ld_bf8(hb + (size_t)b*H_ + i);   // normal cached load (write-once data)
          alo[mt] = ld_bf8(lb + (size_t)b*H_ + i);
        }
        #pragma unroll
        for (int nj = 0; nj < 2; ++nj){
          int holoc = w*32 + nj*16 + lr;
          int byte = holoc*512 + (kk*32 + lk8)*2;
          byte ^= (holoc & 7) << 4;
          bf16x8 bhi = __builtin_bit_cast(bf16x8, *(const uint4*)(lds + byte));
          bf16x8 blo = ld_bf8(cmlo + (((size_t)(d-1)*H_ + n*128 + holoc)*H_ + i));  // cached
          #pragma unroll
          for (int mt = 0; mt < 4; ++mt){
            acc[mt][nj] = __builtin_amdgcn_mfma_f32_16x16x32_bf16(ahi[mt], bhi, acc[mt][nj],0,0,0);
            acc[mt][nj] = __builtin_amdgcn_mfma_f32_16x16x32_bf16(alo[mt], bhi, acc[mt][nj],0,0,0);
            acc[mt][nj] = __builtin_amdgcn_mfma_f32_16x16x32_bf16(ahi[mt], blo, acc[mt][nj],0,0,0);
          }
        }
      }
      // coherent (write-through) partial stores
      #pragma unroll
      for (int mt=0; mt<4; ++mt)
        #pragma unroll
        for (int nj=0; nj<2; ++nj){
          int ho = n*128 + w*32 + nj*16 + lr;
          #pragma unroll
          for (int r2=0;r2<4;++r2){
            int b = mt*16 + (l>>4)*4 + r2;
            st_coh_f32(&partial[((size_t)k*B_ + b)*H_ + ho], acc[mt][nj][r2]);
          }
        }
    } // else: region stays zero from launch-time memset

    gbar(flags, g, tid, 2*t+1);

    // ---- phase R: reduce 32 partials (8 per wave + LDS combine), +aff, tanh, write h ----
    {
      const int b = l;                 // lane = batch row
      float s0=0.f, s1=0.f, s2=0.f, s3=0.f;
      #pragma unroll
      for (int kq = w*8; kq < w*8+8; ++kq){
        const float* pp = partial + ((size_t)kq*B_ + b)*H_ + c0;
        s0 += ld_coh_f32(pp+0);
        s1 += ld_coh_f32(pp+1);
        s2 += ld_coh_f32(pp+2);
        s3 += ld_coh_f32(pp+3);
      }
      if (w) red[w-1][b] = make_float4(s0,s1,s2,s3);
      __syncthreads();
      if (w == 0){
        #pragma unroll
        for (int q=0;q<3;++q){
          float4 r4 = red[q][b];
          s0 += r4.x; s1 += r4.y; s2 += r4.z; s3 += r4.w;
        }
        if (t < T_-1){
          const float* ap = aff + ((size_t)t*B_ + b)*H_ + c0;
          float h0 = tanhf(ap[0] + s0);
          float h1 = tanhf(ap[1] + s1);
          float h2 = tanhf(ap[2] + s2);
          float h3 = tanhf(ap[3] + s3);
          __bf16 hh0=(__bf16)h0, hh1=(__bf16)h1, hh2=(__bf16)h2, hh3=(__bf16)h3;
          __bf16 hl0=(__bf16)(h0-(float)hh0), hl1=(__bf16)(h1-(float)hh1);
          __bf16 hl2=(__bf16)(h2-(float)hh2), hl3=(__bf16)(h3-(float)hh3);
          u32 hi01 = (u32)__builtin_bit_cast(u16,hh0) | ((u32)__builtin_bit_cast(u16,hh1)<<16);
          u32 hi23 = (u32)__builtin_bit_cast(u16,hh2) | ((u32)__builtin_bit_cast(u16,hh3)<<16);
          u32 lo01 = (u32)__builtin_bit_cast(u16,hl0) | ((u32)__builtin_bit_cast(u16,hl1)<<16);
          u32 lo23 = (u32)__builtin_bit_cast(u16,hl2) | ((u32)__builtin_bit_cast(u16,hl3)<<16);
          size_t base = ((size_t)t*B_ + b)*H_ + c0;    // c0 % 4 == 0 -> 8B aligned
          st_coh_u32((u32*)(hhi + base),     hi01);
          st_coh_u32((u32*)(hhi + base) + 1, hi23);
          st_coh_u32((u32*)(hlo + base),     lo01);
          st_coh_u32((u32*)(hlo + base) + 1, lo23);
        } else {
          prelast[(size_t)b*H_ + c0+0] = s0;   // normal stores: next kernel reads
          prelast[(size_t)b*H_ + c0+1] = s1;
          prelast[(size_t)b*H_ + c0+2] = s2;
          prelast[(size_t)b*H_ + c0+3] = s3;
        }
      }
    }

    if (t < T_-1) gbar(flags, g, tid, 2*t+2);
  }
}

// ---------- y[b][o] = pre_last[b][:] . we[o][:] + be[o] (pure f32) ----------
__global__ __launch_bounds__(256) void k_out(const float* __restrict__ prelast,
    const float* __restrict__ we, const float* __restrict__ be, float* __restrict__ y){
  int idx = blockIdx.x*256 + threadIdx.x;
  int b = idx >> 8, o = idx & 255;
  const float4* pa = (const float4*)(prelast + (size_t)b*H_);
  const float4* wb = (const float4*)(we + (size_t)o*H_);
  float s = 0.f;
  #pragma unroll 8
  for (int i2 = 0; i2 < H_/4; ++i2){
    float4 p = pa[i2], q = wb[i2];
    s += p.x*q.x + p.y*q.y + p.z*q.z + p.w*q.w;
  }
  y[idx] = s + be[o];
}

extern "C" void kernel_launch(void* const* d_in, const int* in_sizes, int n_in,
                              void* d_out, int out_size, void* d_ws, size_t ws_size,
                              hipStream_t stream){
  (void)in_sizes; (void)n_in; (void)out_size; (void)ws_size;
  const float* x   = (const float*)d_in[0];
  const float* wa  = (const float*)d_in[1];
  const float* ba  = (const float*)d_in[2];
  const float* lat = (const float*)d_in[3];
  const float* tau = (const float*)d_in[4];
  const float* we  = (const float*)d_in[5];
  const float* be  = (const float*)d_in[6];
  float* y = (float*)d_out;

  char* ws = (char*)d_ws;
  size_t cur = 0;
  auto alloc = [&](size_t sz) -> void* {
    void* p = ws + cur;
    cur += (sz + 255) & ~(size_t)255;
    return p;
  };
  int*   flags   = (int*)  alloc(4096);
  float* partial = (float*)alloc((size_t)NSLICE*B_*H_*4);   // contiguous with flags for one memset
  u16* xhi = (u16*)alloc((size_t)B_*T_*I_*2);
  u16* xlo = (u16*)alloc((size_t)B_*T_*I_*2);
  u16* wahi= (u16*)alloc((size_t)H_*I_*2);
  u16* walo= (u16*)alloc((size_t)H_*I_*2);
  u16* cmhi= (u16*)alloc((size_t)D_*H_*H_*2);
  u16* cmlo= (u16*)alloc((size_t)D_*H_*H_*2);
  float* aff = (float*)alloc((size_t)T_*B_*H_*4);
  u16* hhi = (u16*)alloc((size_t)T_*B_*H_*2);
  u16* hlo = (u16*)alloc((size_t)T_*B_*H_*2);
  float* prelast = (float*)alloc((size_t)B_*H_*4);

  // zero barrier flags + partial accumulators (re-poisoned by harness each launch)
  hipMemsetAsync(flags, 0, 4096 + (size_t)NSLICE*B_*H_*4, stream);

  k_split<<<(B_*T_*I_+255)/256, 256, 0, stream>>>(x, xhi, xlo, B_*T_*I_);
  k_split<<<(H_*I_+255)/256,   256, 0, stream>>>(wa, wahi, walo, H_*I_);
  k_prep_cm<<<(D_*H_*H_+255)/256, 256, 0, stream>>>(tau, lat, cmhi, cmlo);
  k_aff<<<1024, 256, 0, stream>>>(xhi, xlo, wahi, walo, ba, aff);
  k_rec<<<NWG, 256, 0, stream>>>(cmhi, cmlo, aff, hhi, hlo, partial, prelast, flags);
  k_out<<<(B_*O_+255)/256, 256, 0, stream>>>(prelast, we, be, y);
}

// Round 3
// 3183.112 us; speedup vs baseline: 5.6648x; 2.8348x over previous
//
#include <hip/hip_runtime.h>
#include <hip/hip_bf16.h>

typedef unsigned short u16;
typedef unsigned int u32;
typedef __bf16 bf16x8 __attribute__((ext_vector_type(8)));
typedef _Float16 f16x8 __attribute__((ext_vector_type(8)));
typedef float f32x4 __attribute__((ext_vector_type(4)));

#define B_ 64
#define T_ 256
#define I_ 256
#define H_ 512
#define O_ 256
#define D_ 16
#define NWG 128
#define CM_SCALE 64.0f
#define CM_INV   0.015625f

__device__ __forceinline__ bf16x8 ld_bf8(const u16* p){
  uint4 u = *(const uint4*)p;
  return __builtin_bit_cast(bf16x8, u);
}

// ---------- elementwise prep: f32 -> bf16 hi/lo split (afferent GEMM inputs) ----------
__global__ __launch_bounds__(256) void k_split(const float* __restrict__ src,
    u16* __restrict__ hi, u16* __restrict__ lo, int n){
  int i = blockIdx.x*256 + threadIdx.x;
  if (i >= n) return;
  float v = src[i];
  __bf16 h = (__bf16)v;
  __bf16 l = (__bf16)(v - (float)h);
  hi[i] = __builtin_bit_cast(u16, h);
  lo[i] = __builtin_bit_cast(u16, l);
}

// ---------- cm[d][ho][i] = relu(0.125 - |d - clip(tau,1,16)|/64) * lateral, f16 scaled x64 ----------
__global__ __launch_bounds__(256) void k_prep_cm(const float* __restrict__ tau,
    const float* __restrict__ lat, _Float16* __restrict__ cmf){
  int idx = blockIdx.x*256 + threadIdx.x;
  if (idx >= D_*H_*H_) return;
  int d = idx / (H_*H_) + 1;      // 1..16
  int r = idx % (H_*H_);
  float tc = fminf(fmaxf(tau[r], 1.0f), (float)D_);
  float cr = fmaxf(0.0f, 0.125f - fabsf((float)d - tc) * 0.015625f);
  cmf[idx] = (_Float16)(cr * lat[r] * CM_SCALE);
}

// ---------- afferent: acc[t][b][ho] = x[b][t][:] . wa[ho][:] + ba[ho] (3-MFMA bf16 split) ----------
// Writes the afferent preact directly as acc's initial value; also keeps the t=255 slice
// separately (k_out must subtract it: the reference output uses the raw delayed sum).
__global__ __launch_bounds__(256) void k_aff(const u16* __restrict__ xhi,
    const u16* __restrict__ xlo, const u16* __restrict__ wahi,
    const u16* __restrict__ walo, const float* __restrict__ ba,
    float* __restrict__ acc, float* __restrict__ aff_last){
  int g = blockIdx.x;            // 1024 blocks
  int mg = g >> 2, ng = g & 3;   // 64-row m-group, 128-col n-group
  int tid = threadIdx.x;
  int w = tid >> 6, l = tid & 63;
  int lr = l & 15, lk8 = (l >> 4) * 8;
  f32x4 accr[4][2];
  #pragma unroll
  for (int a=0;a<4;++a){ accr[a][0]=(f32x4){0.f,0.f,0.f,0.f}; accr[a][1]=(f32x4){0.f,0.f,0.f,0.f}; }
  #pragma unroll 1
  for (int kk = 0; kk < 8; ++kk){
    int i = kk*32 + lk8;
    bf16x8 ahi[4], alo[4];
    #pragma unroll
    for (int mt = 0; mt < 4; ++mt){
      int r = mg*64 + mt*16 + lr;      // r = t*64 + b
      int t = r >> 6, b = r & 63;
      size_t off = ((size_t)b*T_ + t)*I_ + i;
      ahi[mt] = ld_bf8(xhi + off);
      alo[mt] = ld_bf8(xlo + off);
    }
    #pragma unroll
    for (int nj = 0; nj < 2; ++nj){
      int ho = ng*128 + w*32 + nj*16 + lr;
      bf16x8 bhi = ld_bf8(wahi + (size_t)ho*I_ + i);
      bf16x8 blo = ld_bf8(walo + (size_t)ho*I_ + i);
      #pragma unroll
      for (int mt = 0; mt < 4; ++mt){
        accr[mt][nj] = __builtin_amdgcn_mfma_f32_16x16x32_bf16(ahi[mt], bhi, accr[mt][nj],0,0,0);
        accr[mt][nj] = __builtin_amdgcn_mfma_f32_16x16x32_bf16(alo[mt], bhi, accr[mt][nj],0,0,0);
        accr[mt][nj] = __builtin_amdgcn_mfma_f32_16x16x32_bf16(ahi[mt], blo, accr[mt][nj],0,0,0);
      }
    }
  }
  #pragma unroll
  for (int mt=0; mt<4; ++mt)
    #pragma unroll
    for (int nj=0; nj<2; ++nj){
      int ho = ng*128 + w*32 + nj*16 + lr;
      float bias = ba[ho];
      #pragma unroll
      for (int r2=0;r2<4;++r2){
        int r = mg*64 + mt*16 + (l>>4)*4 + r2;   // r = t*64 + b
        float v = accr[mt][nj][r2] + bias;
        acc[(size_t)r*H_ + ho] = v;
        if ((r >> 6) == T_-1) aff_last[(size_t)(r & 63)*H_ + ho] = v;
      }
    }
}

// ---------- persistent recurrence: gather scheme, one sync point per step ----------
// WG g: n = g&3 (128-col out block), k = g>>2: d = (k>>1)+1, i0 = (k&1)*256 (K-slice).
// Step t (t>=d): h(t-d) = tanh(acc[t-d]) on this WG's [64 x 256] A-slab (redundant,
// deterministic), MFMA vs LDS-resident cm[d] slice, atomicAdd into acc[t].
__global__ __launch_bounds__(256) void k_rec(const _Float16* __restrict__ cmf,
    float* __restrict__ acc, int* __restrict__ flags){
  __shared__ char lds[98304];          // [0,64K): cm slice [128][256] f16 swz; [64K,96K): h [64][256] f16 swz
  char* ldsB = lds;
  char* ldsA = lds + 65536;
  const int g = blockIdx.x;
  const int n = g & 3;
  const int k = g >> 2;
  const int d = (k >> 1) + 1;
  const int i0 = (k & 1) * 256;
  const int tid = threadIdx.x;
  const int w = tid >> 6, l = tid & 63;
  const int lr = l & 15, lkg = l >> 4;

  // stage cm slice into LDS (once)
  for (int it = tid; it < 4096; it += 256){
    int ho = it >> 5;
    int c8 = (it & 31) * 8;
    f16x8 v = *(const f16x8*)(cmf + (((size_t)(d-1)*H_ + n*128 + ho)*H_ + i0 + c8));
    int byte = (ho*512 + c8*2) ^ ((ho & 7) << 4);
    *(f16x8*)(ldsB + byte) = v;
  }
  __syncthreads();

  const int arow  = tid >> 2;          // batch row this thread packs
  const int acol0 = (tid & 3) * 64;    // 64-col chunk

  for (int t = 0; t < T_; ++t){
    // ---- wait: acc[t-d] complete <=> all WGs finished step t-d ----
    int needed = t - d + 1;
    if (tid < 64 && needed > 0){
      while (true){
        int f0 = __hip_atomic_load(flags + 2*tid,   __ATOMIC_RELAXED, __HIP_MEMORY_SCOPE_AGENT);
        int f1 = __hip_atomic_load(flags + 2*tid+1, __ATOMIC_RELAXED, __HIP_MEMORY_SCOPE_AGENT);
        if (__all(f0 >= needed && f1 >= needed)) break;
        __builtin_amdgcn_s_sleep(1);
      }
    }
    __syncthreads();

    if (t >= d){
      // ---- load acc[t-d] slab (MALL-coherent), tanh, pack f16 into ldsA ----
      {
        f32x4 arr[16];
        const float* src = acc + ((size_t)(t-d)*B_ + arow)*H_ + i0 + acol0;
        #pragma unroll
        for (int j = 0; j < 16; ++j){
          asm volatile("global_load_dwordx4 %0, %1, off sc0 sc1"
                       : "=v"(arr[j]) : "v"(src + j*4));
        }
        asm volatile("s_waitcnt vmcnt(0)" ::: "memory");
        __builtin_amdgcn_sched_barrier(0);
        #pragma unroll
        for (int c8 = 0; c8 < 8; ++c8){
          f16x8 hh;
          #pragma unroll
          for (int e = 0; e < 8; ++e){
            float x = arr[c8*2 + (e>>2)][e & 3];
            float ex = __expf(2.0f * x);
            float hv = 1.0f - __fdividef(2.0f, ex + 1.0f);
            hh[e] = (_Float16)hv;
          }
          int byte = ((arow*512) + (acol0 + c8*8)*2) ^ ((arow & 7) << 4);
          *(f16x8*)(ldsA + byte) = hh;
        }
      }
      __syncthreads();

      // ---- MFMA: [64 x 256] x cm^T [128 x 256] ----
      f32x4 accr[4][2];
      #pragma unroll
      for (int a=0;a<4;++a){ accr[a][0]=(f32x4){0.f,0.f,0.f,0.f}; accr[a][1]=(f32x4){0.f,0.f,0.f,0.f}; }
      #pragma unroll 1
      for (int kk = 0; kk < 8; ++kk){
        int kb = (kk*32 + lkg*8) * 2;
        f16x8 afr[4];
        #pragma unroll
        for (int mt = 0; mt < 4; ++mt){
          int row = mt*16 + lr;
          afr[mt] = *(const f16x8*)(ldsA + ((row*512 + kb) ^ ((row & 7) << 4)));
        }
        #pragma unroll
        for (int nj = 0; nj < 2; ++nj){
          int ho = w*32 + nj*16 + lr;
          f16x8 bfr = *(const f16x8*)(ldsB + ((ho*512 + kb) ^ ((ho & 7) << 4)));
          #pragma unroll
          for (int mt = 0; mt < 4; ++mt)
            accr[mt][nj] = __builtin_amdgcn_mfma_f32_16x16x32_f16(afr[mt], bfr, accr[mt][nj],0,0,0);
        }
      }

      // ---- scatter: atomicAdd into acc[t] (device-scope f32 adds) ----
      float* dst = acc + (size_t)t*B_*H_ + n*128;
      #pragma unroll
      for (int mt=0; mt<4; ++mt)
        #pragma unroll
        for (int nj=0; nj<2; ++nj){
          int ho = w*32 + nj*16 + lr;
          #pragma unroll
          for (int r2=0;r2<4;++r2){
            int b = mt*16 + (l>>4)*4 + r2;
            atomicAdd(dst + (size_t)b*H_ + ho, accr[mt][nj][r2] * CM_INV);
          }
        }
    }

    // ---- publish: my adds are globally visible, then flag step t done ----
    asm volatile("s_waitcnt vmcnt(0)" ::: "memory");
    __syncthreads();
    if (tid == 0)
      __hip_atomic_store(flags + g, t+1, __ATOMIC_RELAXED, __HIP_MEMORY_SCOPE_AGENT);
  }
}

// ---------- y[b][o] = (acc[255] - aff[255])[b][:] . we[o][:] + be[o] (f32) ----------
__global__ __launch_bounds__(256) void k_out(const float* __restrict__ acc255,
    const float* __restrict__ aff_last, const float* __restrict__ we,
    const float* __restrict__ be, float* __restrict__ y){
  int idx = blockIdx.x*256 + threadIdx.x;
  int b = idx >> 8, o = idx & 255;
  const float4* pa = (const float4*)(acc255 + (size_t)b*H_);
  const float4* pf = (const float4*)(aff_last + (size_t)b*H_);
  const float4* wb = (const float4*)(we + (size_t)o*H_);
  float s = 0.f;
  #pragma unroll 8
  for (int i2 = 0; i2 < H_/4; ++i2){
    float4 p = pa[i2], f = pf[i2], q = wb[i2];
    s += (p.x-f.x)*q.x + (p.y-f.y)*q.y + (p.z-f.z)*q.z + (p.w-f.w)*q.w;
  }
  y[idx] = s + be[o];
}

extern "C" void kernel_launch(void* const* d_in, const int* in_sizes, int n_in,
                              void* d_out, int out_size, void* d_ws, size_t ws_size,
                              hipStream_t stream){
  (void)in_sizes; (void)n_in; (void)out_size; (void)ws_size;
  const float* x   = (const float*)d_in[0];
  const float* wa  = (const float*)d_in[1];
  const float* ba  = (const float*)d_in[2];
  const float* lat = (const float*)d_in[3];
  const float* tau = (const float*)d_in[4];
  const float* we  = (const float*)d_in[5];
  const float* be  = (const float*)d_in[6];
  float* y = (float*)d_out;

  char* ws = (char*)d_ws;
  size_t cur = 0;
  auto alloc = [&](size_t sz) -> void* {
    void* p = ws + cur;
    cur += (sz + 255) & ~(size_t)255;
    return p;
  };
  int*      flags    = (int*)     alloc(4096);
  float*    acc      = (float*)   alloc((size_t)T_*B_*H_*4);   // 33.5 MB preact accumulators
  float*    aff_last = (float*)   alloc((size_t)B_*H_*4);
  u16*      xhi      = (u16*)     alloc((size_t)B_*T_*I_*2);
  u16*      xlo      = (u16*)     alloc((size_t)B_*T_*I_*2);
  u16*      wahi     = (u16*)     alloc((size_t)H_*I_*2);
  u16*      walo     = (u16*)     alloc((size_t)H_*I_*2);
  _Float16* cmf      = (_Float16*)alloc((size_t)D_*H_*H_*2);

  // only the barrier flags need zeroing (acc is fully initialized by k_aff)
  hipMemsetAsync(flags, 0, 4096, stream);

  k_split<<<(B_*T_*I_+255)/256, 256, 0, stream>>>(x, xhi, xlo, B_*T_*I_);
  k_split<<<(H_*I_+255)/256,   256, 0, stream>>>(wa, wahi, walo, H_*I_);
  k_prep_cm<<<(D_*H_*H_+255)/256, 256, 0, stream>>>(tau, lat, cmf);
  k_aff<<<1024, 256, 0, stream>>>(xhi, xlo, wahi, walo, ba, acc, aff_last);
  k_rec<<<NWG, 256, 0, stream>>>(cmf, acc, flags);
  k_out<<<(B_*O_+255)/256, 256, 0, stream>>>(acc + (size_t)(T_-1)*B_*H_, aff_last, we, be, y);
}

// Round 6
// 2736.662 us; speedup vs baseline: 6.5890x; 1.1631x over previous
//
#include <hip/hip_runtime.h>
#include <hip/hip_bf16.h>

typedef unsigned short u16;
typedef unsigned int u32;
typedef __bf16 bf16x8 __attribute__((ext_vector_type(8)));
typedef _Float16 f16x8 __attribute__((ext_vector_type(8)));
typedef float f32x4 __attribute__((ext_vector_type(4)));

#define B_ 64
#define T_ 256
#define I_ 256
#define H_ 512
#define O_ 256
#define D_ 16
#define NWG 128
#define CM_SCALE 64.0f
#define CM_INV   0.015625f

__device__ __forceinline__ bf16x8 ld_bf8(const u16* p){
  uint4 u = *(const uint4*)p;
  return __builtin_bit_cast(bf16x8, u);
}

// ---------- elementwise prep: f32 -> bf16 hi/lo split (afferent GEMM inputs) ----------
__global__ __launch_bounds__(256) void k_split(const float* __restrict__ src,
    u16* __restrict__ hi, u16* __restrict__ lo, int n){
  int i = blockIdx.x*256 + threadIdx.x;
  if (i >= n) return;
  float v = src[i];
  __bf16 h = (__bf16)v;
  __bf16 l = (__bf16)(v - (float)h);
  hi[i] = __builtin_bit_cast(u16, h);
  lo[i] = __builtin_bit_cast(u16, l);
}

// ---------- cm[d][ho][i] = relu(0.125 - |d - clip(tau,1,16)|/64) * lateral, f16 scaled x64 ----------
__global__ __launch_bounds__(256) void k_prep_cm(const float* __restrict__ tau,
    const float* __restrict__ lat, _Float16* __restrict__ cmf){
  int idx = blockIdx.x*256 + threadIdx.x;
  if (idx >= D_*H_*H_) return;
  int d = idx / (H_*H_) + 1;      // 1..16
  int r = idx % (H_*H_);
  float tc = fminf(fmaxf(tau[r], 1.0f), (float)D_);
  float cr = fmaxf(0.0f, 0.125f - fabsf((float)d - tc) * 0.015625f);
  cmf[idx] = (_Float16)(cr * lat[r] * CM_SCALE);
}

// ---------- afferent: acc[t][b][ho] = x[b][t][:] . wa[ho][:] + ba[ho] (3-MFMA bf16 split) ----------
__global__ __launch_bounds__(256) void k_aff(const u16* __restrict__ xhi,
    const u16* __restrict__ xlo, const u16* __restrict__ wahi,
    const u16* __restrict__ walo, const float* __restrict__ ba,
    float* __restrict__ acc, float* __restrict__ aff_last){
  int g = blockIdx.x;            // 1024 blocks
  int mg = g >> 2, ng = g & 3;   // 64-row m-group, 128-col n-group
  int tid = threadIdx.x;
  int w = tid >> 6, l = tid & 63;
  int lr = l & 15, lk8 = (l >> 4) * 8;
  f32x4 accr[4][2];
  #pragma unroll
  for (int a=0;a<4;++a){ accr[a][0]=(f32x4){0.f,0.f,0.f,0.f}; accr[a][1]=(f32x4){0.f,0.f,0.f,0.f}; }
  #pragma unroll 1
  for (int kk = 0; kk < 8; ++kk){
    int i = kk*32 + lk8;
    bf16x8 ahi[4], alo[4];
    #pragma unroll
    for (int mt = 0; mt < 4; ++mt){
      int r = mg*64 + mt*16 + lr;      // r = t*64 + b
      int t = r >> 6, b = r & 63;
      size_t off = ((size_t)b*T_ + t)*I_ + i;
      ahi[mt] = ld_bf8(xhi + off);
      alo[mt] = ld_bf8(xlo + off);
    }
    #pragma unroll
    for (int nj = 0; nj < 2; ++nj){
      int ho = ng*128 + w*32 + nj*16 + lr;
      bf16x8 bhi = ld_bf8(wahi + (size_t)ho*I_ + i);
      bf16x8 blo = ld_bf8(walo + (size_t)ho*I_ + i);
      #pragma unroll
      for (int mt = 0; mt < 4; ++mt){
        accr[mt][nj] = __builtin_amdgcn_mfma_f32_16x16x32_bf16(ahi[mt], bhi, accr[mt][nj],0,0,0);
        accr[mt][nj] = __builtin_amdgcn_mfma_f32_16x16x32_bf16(alo[mt], bhi, accr[mt][nj],0,0,0);
        accr[mt][nj] = __builtin_amdgcn_mfma_f32_16x16x32_bf16(ahi[mt], blo, accr[mt][nj],0,0,0);
      }
    }
  }
  #pragma unroll
  for (int mt=0; mt<4; ++mt)
    #pragma unroll
    for (int nj=0; nj<2; ++nj){
      int ho = ng*128 + w*32 + nj*16 + lr;
      float bias = ba[ho];
      #pragma unroll
      for (int r2=0;r2<4;++r2){
        int r = mg*64 + mt*16 + (l>>4)*4 + r2;   // r = t*64 + b
        float v = accr[mt][nj][r2] + bias;
        acc[(size_t)r*H_ + ho] = v;
        if ((r >> 6) == T_-1) aff_last[(size_t)(r & 63)*H_ + ho] = v;
      }
    }
}

// ---------- persistent recurrence: gather scheme, counter barrier ----------
// WG g: n = g&3 (128-col out block), k = g>>2: d = (k>>1)+1, i0 = (k&1)*256 (K-slice).
// Step t (t>=d): h(t-d) = tanh(acc[t-d]) on this WG's [64 x 256] A-slab (redundant,
// deterministic), MFMA vs LDS-resident cm[d] slice, atomicAdd into acc[t].
// acc[t] complete <=> ctr[t] == NWG (each WG increments after its atomics drained).
__global__ __launch_bounds__(256) void k_rec(const _Float16* __restrict__ cmf,
    float* __restrict__ acc, int* __restrict__ ctr){
  __shared__ char lds[98304];          // [0,64K): cm slice [128][256] f16 swz; [64K,96K): h [64][256] f16 swz
  char* ldsB = lds;
  char* ldsA = lds + 65536;
  const int g = blockIdx.x;
  const int n = g & 3;
  const int k = g >> 2;
  const int d = (k >> 1) + 1;
  const int i0 = (k & 1) * 256;
  const int tid = threadIdx.x;
  const int w = tid >> 6, l = tid & 63;
  const int lr = l & 15, lkg = l >> 4;

  // stage cm slice into LDS (once)
  for (int it = tid; it < 4096; it += 256){
    int ho = it >> 5;
    int c8 = (it & 31) * 8;
    f16x8 v = *(const f16x8*)(cmf + (((size_t)(d-1)*H_ + n*128 + ho)*H_ + i0 + c8));
    int byte = (ho*512 + c8*2) ^ ((ho & 7) << 4);
    *(f16x8*)(ldsB + byte) = v;
  }
  __syncthreads();

  const int arow = tid >> 2;           // pack: batch row this thread handles
  const int q    = tid & 3;
  const int cofs = q + ((arow & 1) << 2);  // chunk offset: conflict-free write slots
                                           // (even rows: blocks {4j..}, odd rows: +4 -> disjoint)

  for (int t = 0; t < T_; ++t){
    if (t >= d){
      // ---- wait: acc[t-d] complete ----
      if (tid == 0){
        while (__hip_atomic_load(ctr + (t-d), __ATOMIC_RELAXED, __HIP_MEMORY_SCOPE_AGENT) < NWG)
          __builtin_amdgcn_s_sleep(1);
      }
      __syncthreads();

      // ---- load acc[t-d] slab (LLC-coherent), tanh, pack f16 into ldsA ----
      {
        f32x4 arr[16];
        const float* srow = acc + ((size_t)(t-d)*B_ + arow)*H_ + i0;
        #pragma unroll
        for (int j = 0; j < 8; ++j){
          int c = (4*j + cofs) & 31;   // runtime addr math only; arr index compile-time
          asm volatile("global_load_dwordx4 %0, %1, off sc0 sc1"
                       : "=v"(arr[2*j])   : "v"(srow + c*8));
          asm volatile("global_load_dwordx4 %0, %1, off sc0 sc1"
                       : "=v"(arr[2*j+1]) : "v"(srow + c*8 + 4));
        }
        asm volatile("s_waitcnt vmcnt(0)" ::: "memory");
        __builtin_amdgcn_sched_barrier(0);
        #pragma unroll
        for (int j = 0; j < 8; ++j){
          int c = (4*j + cofs) & 31;
          f16x8 hh;
          #pragma unroll
          for (int e = 0; e < 8; ++e){
            float x = arr[2*j + (e>>2)][e & 3];
            float ex = __expf(2.0f * x);
            float hv = 1.0f - __fdividef(2.0f, ex + 1.0f);
            hh[e] = (_Float16)hv;
          }
          int byte = (arow*512 + c*16) ^ ((arow & 7) << 4);
          *(f16x8*)(ldsA + byte) = hh;
        }
      }
      __syncthreads();

      // ---- MFMA: [64 x 256] x cm^T [128 x 256] ----
      f32x4 accr[4][2];
      #pragma unroll
      for (int a=0;a<4;++a){ accr[a][0]=(f32x4){0.f,0.f,0.f,0.f}; accr[a][1]=(f32x4){0.f,0.f,0.f,0.f}; }
      #pragma unroll 1
      for (int kk = 0; kk < 8; ++kk){
        int kb = (kk*32 + lkg*8) * 2;
        f16x8 afr[4];
        #pragma unroll
        for (int mt = 0; mt < 4; ++mt){
          int row = mt*16 + lr;
          afr[mt] = *(const f16x8*)(ldsA + ((row*512 + kb) ^ ((row & 7) << 4)));
        }
        #pragma unroll
        for (int nj = 0; nj < 2; ++nj){
          int ho = w*32 + nj*16 + lr;
          f16x8 bfr = *(const f16x8*)(ldsB + ((ho*512 + kb) ^ ((ho & 7) << 4)));
          #pragma unroll
          for (int mt = 0; mt < 4; ++mt)
            accr[mt][nj] = __builtin_amdgcn_mfma_f32_16x16x32_f16(afr[mt], bfr, accr[mt][nj],0,0,0);
        }
      }

      // ---- scatter: atomicAdd into acc[t] ----
      float* dst = acc + (size_t)t*B_*H_ + n*128;
      #pragma unroll
      for (int mt=0; mt<4; ++mt)
        #pragma unroll
        for (int nj=0; nj<2; ++nj){
          int ho = w*32 + nj*16 + lr;
          #pragma unroll
          for (int r2=0;r2<4;++r2){
            int b = mt*16 + (l>>4)*4 + r2;
            atomicAdd(dst + (size_t)b*H_ + ho, accr[mt][nj][r2] * CM_INV);
          }
        }
    }

    // ---- publish: my adds globally visible, then count step t done ----
    asm volatile("s_waitcnt vmcnt(0)" ::: "memory");
    __syncthreads();
    if (tid == 0)
      __hip_atomic_fetch_add(ctr + t, 1, __ATOMIC_RELAXED, __HIP_MEMORY_SCOPE_AGENT);
  }
}

// ---------- y[b][o] = (acc[255] - aff[255])[b][:] . we[o][:] + be[o] (f32) ----------
__global__ __launch_bounds__(256) void k_out(const float* __restrict__ acc255,
    const float* __restrict__ aff_last, const float* __restrict__ we,
    const float* __restrict__ be, float* __restrict__ y){
  int idx = blockIdx.x*256 + threadIdx.x;
  int b = idx >> 8, o = idx & 255;
  const float4* pa = (const float4*)(acc255 + (size_t)b*H_);
  const float4* pf = (const float4*)(aff_last + (size_t)b*H_);
  const float4* wb = (const float4*)(we + (size_t)o*H_);
  float s = 0.f;
  #pragma unroll 8
  for (int i2 = 0; i2 < H_/4; ++i2){
    float4 p = pa[i2], f = pf[i2], q = wb[i2];
    s += (p.x-f.x)*q.x + (p.y-f.y)*q.y + (p.z-f.z)*q.z + (p.w-f.w)*q.w;
  }
  y[idx] = s + be[o];
}

extern "C" void kernel_launch(void* const* d_in, const int* in_sizes, int n_in,
                              void* d_out, int out_size, void* d_ws, size_t ws_size,
                              hipStream_t stream){
  (void)in_sizes; (void)n_in; (void)out_size; (void)ws_size;
  const float* x   = (const float*)d_in[0];
  const float* wa  = (const float*)d_in[1];
  const float* ba  = (const float*)d_in[2];
  const float* lat = (const float*)d_in[3];
  const float* tau = (const float*)d_in[4];
  const float* we  = (const float*)d_in[5];
  const float* be  = (const float*)d_in[6];
  float* y = (float*)d_out;

  char* ws = (char*)d_ws;
  size_t cur = 0;
  auto alloc = [&](size_t sz) -> void* {
    void* p = ws + cur;
    cur += (sz + 255) & ~(size_t)255;
    return p;
  };
  int*      ctr      = (int*)     alloc(4096);                 // per-step completion counters
  float*    acc      = (float*)   alloc((size_t)T_*B_*H_*4);   // 33.5 MB preact accumulators
  float*    aff_last = (float*)   alloc((size_t)B_*H_*4);
  u16*      xhi      = (u16*)     alloc((size_t)B_*T_*I_*2);
  u16*      xlo      = (u16*)     alloc((size_t)B_*T_*I_*2);
  u16*      wahi     = (u16*)     alloc((size_t)H_*I_*2);
  u16*      walo     = (u16*)     alloc((size_t)H_*I_*2);
  _Float16* cmf      = (_Float16*)alloc((size_t)D_*H_*H_*2);

  // only the counters need zeroing (acc is fully initialized by k_aff)
  hipMemsetAsync(ctr, 0, 4096, stream);

  k_split<<<(B_*T_*I_+255)/256, 256, 0, stream>>>(x, xhi, xlo, B_*T_*I_);
  k_split<<<(H_*I_+255)/256,   256, 0, stream>>>(wa, wahi, walo, H_*I_);
  k_prep_cm<<<(D_*H_*H_+255)/256, 256, 0, stream>>>(tau, lat, cmf);
  k_aff<<<1024, 256, 0, stream>>>(xhi, xlo, wahi, walo, ba, acc, aff_last);
  k_rec<<<NWG, 256, 0, stream>>>(cmf, acc, ctr);
  k_out<<<(B_*O_+255)/256, 256, 0, stream>>>(acc + (size_t)(T_-1)*B_*H_, aff_last, we, be, y);
}